// Round 14
// baseline (251.578 us; speedup 1.0000x reference)
//
#include <hip/hip_runtime.h>
#include <hip/hip_fp16.h>

// Self-attention B=8 S=2048 D=512, fp32-vs-bf16 input auto-detect.
// R22 = R21 (251.5 us best) + ONE single-variable test: scores moves to a
// conflict-free 16x16x32-fragment kernel (gemm_sc) with IDENTICAL geometry
// (128x128 tile, 4 waves, 32KB LDS, same staging/swizzle/grid). R21
// counters: scores is top (57.2us, 4.19M bank-conflict cycles ~= 7us);
// the 16x16 XOR read path is HW-verified conflict-free (R11/R18/pv64 all
// measured SQ_LDS_BANK_CONFLICT=0) and pv64's 16x16 beat 32x32 PV 614 vs
// 582 TF. R12's 16x16 null was confounded (2-wave). Wave = 64x64 = 4x4
// frags, formulas verbatim from verified pv64/R11 code.
// Decision rule: scores >= 56.5us => conflict lever conclusively null,
// revert to R21 and declare the structural plateau.
// History: R13 xy-swz; R14 v-transpose; R15/R19 z-fold; R20 fp16 scores
// -22us; R21 pv64 +0.7; R9/R11/R12/R16/R18 schedule rewrites regressed.

typedef unsigned short u16;
typedef unsigned int u32;
typedef __attribute__((ext_vector_type(8))) _Float16 f16x8;
typedef __attribute__((ext_vector_type(16))) float f32x16;
typedef __attribute__((ext_vector_type(4))) float f32x4;

#define S_LEN 2048
#define D_DIM 512
#define B_N 8

__device__ __forceinline__ u16 f2bf(float f) {
    u32 u = __float_as_uint(f);
    u32 r = u + 0x7FFFu + ((u >> 16) & 1u);   // RNE
    return (u16)(r >> 16);
}
__device__ __forceinline__ float bf2f(u16 h) {
    return __uint_as_float((u32)h << 16);
}
__device__ __forceinline__ u16 f2h(float f) {
    _Float16 h = (_Float16)f;                 // RNE
    return *(u16*)&h;
}
__device__ __forceinline__ void gl16(const u16* g, u16* l) {
    __builtin_amdgcn_global_load_lds(
        (const __attribute__((address_space(1))) void*)g,
        (__attribute__((address_space(3))) void*)l, 16, 0, 0);
}
__device__ __forceinline__ f32x16 mfma16(f16x8 a, f16x8 b, f32x16 c) {
    return __builtin_amdgcn_mfma_f32_32x32x16_f16(a, b, c, 0, 0, 0);
}
__device__ __forceinline__ f32x4 mfma16q(f16x8 a, f16x8 b, f32x4 c) {
    return __builtin_amdgcn_mfma_f32_16x16x32_f16(a, b, c, 0, 0, 0);
}

// ---- dtype detector ----
__global__ void detect_k(const u16* __restrict__ x, int* __restrict__ flag)
{
    int t = threadIdx.x;
    u16 u = x[2 * t];
    int e = (u >> 7) & 0xFF;
    int sane = (e == 0) || (e >= 110 && e <= 140);
    unsigned long long b = __ballot(sane);
    if (t == 0) *flag = (__popcll(b) >= 32) ? 1 : 0;
}

// ---- convert x to fp16 ----
__global__ __launch_bounds__(256) void cvt_x(
    const void* __restrict__ X, u16* __restrict__ xf,
    const int* __restrict__ flagp)
{
    const size_t i4 = ((size_t)blockIdx.x * 256 + threadIdx.x) * 4;
    float f[4];
    if (*flagp) {
        ushort4 u = *(const ushort4*)((const u16*)X + i4);
        f[0] = bf2f(u.x); f[1] = bf2f(u.y); f[2] = bf2f(u.z); f[3] = bf2f(u.w);
    } else {
        float4 ff = *(const float4*)((const float*)X + i4);
        f[0] = ff.x; f[1] = ff.y; f[2] = ff.z; f[3] = ff.w;
    }
    ushort4 h;
    h.x = f2h(f[0]); h.y = f2h(f[1]); h.z = f2h(f[2]); h.w = f2h(f[3]);
    *(ushort4*)(xf + i4) = h;
}

// ---- pack W^T concat (q|k|v) fp16: WT[n 0..1535][k 0..511] ----
__global__ __launch_bounds__(256) void pack_w(
    const void* __restrict__ Wq, const void* __restrict__ Wk, const void* __restrict__ Wv,
    u16* __restrict__ WT, const int* __restrict__ flagp)
{
    const int k = blockIdx.x;
    const int n = blockIdx.y * 256 + threadIdx.x;
    const void* W = n < 512 ? Wq : n < 1024 ? Wk : Wv;
    const int nc = n & 511;
    float f = *flagp ? bf2f(((const u16*)W)[(size_t)k * 512 + nc])
                     : ((const float*)W)[(size_t)k * 512 + nc];
    WT[(size_t)n * 512 + k] = f2h(f);
}

__global__ void pack_bias(
    const void* __restrict__ bq, const void* __restrict__ bk, const void* __restrict__ bv,
    float* __restrict__ bcat, const int* __restrict__ flagp)
{
    const int t = blockIdx.x * 256 + threadIdx.x;
    const void* b = t < 512 ? bq : t < 1024 ? bk : bv;
    const int i = t & 511;
    bcat[t] = *flagp ? bf2f(((const u16*)b)[i]) : ((const float*)b)[i];
}

// ---- proj fp16 BT-GEMM (EPI2 only now): C[M,N] = A[M,K] * B[N,K]^T ----
// 128x128 tile, BK=64. Staging: slot s of row r holds global chunk s^(r&7).
// z-fold chunked XCD swizzle; proj q|k|vT(+LDS transpose) +bias.
template <int EPI>
__global__ __launch_bounds__(256) void gemm_f16(
    const u16* __restrict__ A_, const u16* __restrict__ B_,
    void* __restrict__ Cp, const float* __restrict__ biasf,
    u16* __restrict__ Oq, u16* __restrict__ Ok, u16* __restrict__ OvT,
    const int* __restrict__ flagp,
    int K, int lda, int ldb, int ldc, long sA, long sB, long sC, long cbase)
{
    const int tid = threadIdx.x;
    const int lane = tid & 63, wav = tid >> 6;
    const int l31 = lane & 31, lh = lane >> 5;

    // ---- XCD-aware chunked swizzle of the z-major linear id ----
    const int gx = gridDim.x, gy = gridDim.y;
    const int total = gx * gy * gridDim.z;
    const int chunk = total >> 3;              // total % 8 == 0
    int lin = (blockIdx.z * gy + blockIdx.y) * gx + blockIdx.x;
    lin = (lin & 7) * chunk + (lin >> 3);
    const int bx = lin % gx;
    const int by = (lin / gx) % gy;
    const int bz = lin / (gx * gy);

    const int m0 = by * 128, n0 = bx * 128;
    const int bm = (wav >> 1) * 64, bn = (wav & 1) * 64;

    const u16* A = A_ + (size_t)bz * sA;
    const u16* B = B_ + (size_t)bz * sB;

    // 32 KiB union: K-loop uses As|Bs halves; EPI2 v-mode reuses all of it
    // as a 128x128 fp16 transpose buffer after the final barrier.
    __shared__ __align__(16) u16 sh[16384];
    u16* As = sh;
    u16* Bs = sh + 8192;

    const int r0 = tid >> 3;
    const int c0 = ((tid & 7) ^ (r0 & 7)) * 8;
    size_t aoff[4], boff[4];
#pragma unroll
    for (int j = 0; j < 4; j++) {
        aoff[j] = (size_t)(m0 + r0 + j * 32) * lda + c0;
        boff[j] = (size_t)(n0 + r0 + j * 32) * ldb + c0;
    }
    const int g7 = l31 & 7;
    const int rowA0 = (bm + l31) * 64, rowA1 = (bm + 32 + l31) * 64;
    const int rowB0 = (bn + l31) * 64, rowB1 = (bn + 32 + l31) * 64;

    f32x16 acc[2][2];
#pragma unroll
    for (int i = 0; i < 2; i++)
#pragma unroll
        for (int j = 0; j < 2; j++)
#pragma unroll
            for (int r = 0; r < 16; r++) acc[i][j][r] = 0.f;

    for (int k0 = 0; k0 < K; k0 += 64) {
#pragma unroll
        for (int j = 0; j < 4; j++) {
            gl16(A + aoff[j] + k0, As + j * 2048 + wav * 512);
            gl16(B + boff[j] + k0, Bs + j * 2048 + wav * 512);
        }
        __syncthreads();

#pragma unroll
        for (int h = 0; h < 4; h++) {
            const int so = ((h * 2 + lh) ^ g7) * 8;
            f16x8 af[2], bfr[2];
            af[0] = *(const f16x8*)&As[rowA0 + so];
            af[1] = *(const f16x8*)&As[rowA1 + so];
            bfr[0] = *(const f16x8*)&Bs[rowB0 + so];
            bfr[1] = *(const f16x8*)&Bs[rowB1 + so];
#pragma unroll
            for (int i = 0; i < 2; i++)
#pragma unroll
                for (int j = 0; j < 2; j++)
                    acc[i][j] = mfma16(af[i], bfr[j], acc[i][j]);
        }
        __syncthreads();
    }

    // ---- epilogue: 32x32 C/D layout col=lane&31, row=(r&3)+8*(r>>2)+4*lh ----
    if (EPI == 2) {
        const int mode = bx >> 2;   // 0=q 1=k 2=v (logical bx)
        if (mode == 2) {
            // v: transpose 128x128 tile through LDS, coalesced vT stores.
#pragma unroll
            for (int it = 0; it < 2; it++)
#pragma unroll
                for (int jt = 0; jt < 2; jt++) {
                    const int lc = bn + jt * 32 + l31;          // 0..127
                    const float badd = biasf[n0 + lc];
#pragma unroll
                    for (int r = 0; r < 16; r++) {
                        const int row = bm + it * 32 + (r & 3) + 8 * (r >> 2) + 4 * lh;
                        sh[lc * 128 + (row ^ ((lc & 15) << 3))] =
                            f2h(acc[it][jt][r] + badd);
                    }
                }
            __syncthreads();
            const int vbase = n0 - 1024;                        // v col offset
#pragma unroll
            for (int p = 0; p < 8; p++) {
                const int q = p * 256 + tid;                    // 0..2047
                const int lc = q >> 4, ch = q & 15;
                const int g = ch ^ (lc & 15);
                f16x8 val = *(const f16x8*)&sh[lc * 128 + g * 8];
                *(f16x8*)&OvT[(size_t)(vbase + lc) * 16384 + m0 + ch * 8] = val;
            }
        } else {
#pragma unroll
            for (int it = 0; it < 2; it++)
#pragma unroll
                for (int jt = 0; jt < 2; jt++) {
                    const int gcol = n0 + bn + jt * 32 + l31;
                    const int lcol = gcol & 511;
                    const float badd = biasf[gcol];
#pragma unroll
                    for (int r = 0; r < 16; r++) {
                        const int row = m0 + bm + it * 32 + (r & 3) + 8 * (r >> 2) + 4 * lh;
                        const float v = acc[it][jt][r] + badd;
                        if (mode == 0) Oq[(size_t)row * 512 + lcol] = f2h(v);
                        else           Ok[(size_t)row * 512 + lcol] = f2h(v);
                    }
                }
        }
    } else {
        // (unused in R22 launches; kept for fallback)
        u16* Ch = (u16*)Cp;
        const long coff = (long)bz * sC;
#pragma unroll
        for (int it = 0; it < 2; it++)
#pragma unroll
            for (int jt = 0; jt < 2; jt++) {
                const int col = n0 + bn + jt * 32 + l31;
#pragma unroll
                for (int r = 0; r < 16; r++) {
                    const int row = m0 + bm + it * 32 + (r & 3) + 8 * (r >> 2) + 4 * lh;
                    Ch[(size_t)(coff + (long)row * ldc + col)] = f2h(acc[it][jt][r]);
                }
            }
    }
}

// ---- scores GEMM, conflict-free 16x16 frags: C[M,N] = q k^T, fp16 out ----
// Identical geometry to the 32x32 scores kernel (128x128 tile, 4 waves,
// BK=64, 32KB LDS, same staging/swizzle/grid); ONLY the fragment shape and
// LDS read pattern change. Wave = 64x64 = 4x4 frags of 16x16x32.
// Read formulas verbatim from pv64/R11 (HW-verified conflict-free).
__global__ __launch_bounds__(256) void gemm_sc(
    const u16* __restrict__ A_, const u16* __restrict__ B_,
    u16* __restrict__ C,
    int K, int lda, int ldb, int ldc, long sA, long sB, long sC)
{
    const int tid = threadIdx.x;
    const int lane = tid & 63, wav = tid >> 6;
    const int l15 = lane & 15, lq = lane >> 4;
    const int bm = (wav >> 1) * 64, bn = (wav & 1) * 64;

    // z-fold chunked XCD swizzle (total = 256c, % 8 == 0)
    const int gx = gridDim.x, gy = gridDim.y;
    const int total = gx * gy * gridDim.z;
    const int chunk = total >> 3;
    int lin = (blockIdx.z * gy + blockIdx.y) * gx + blockIdx.x;
    lin = (lin & 7) * chunk + (lin >> 3);
    const int bx = lin % gx;
    const int by = (lin / gx) % gy;
    const int bz = lin / (gx * gy);

    const int m0 = by * 128, n0 = bx * 128;

    const u16* A = A_ + (size_t)bz * sA;
    const u16* B = B_ + (size_t)bz * sB;

    __shared__ __align__(16) u16 As[8192], Bs[8192];   // 128 x 64 fp16 each

    const int r0 = tid >> 3;
    const int c0 = ((tid & 7) ^ (r0 & 7)) * 8;
    size_t aoff[4], boff[4];
#pragma unroll
    for (int j = 0; j < 4; j++) {
        aoff[j] = (size_t)(m0 + r0 + j * 32) * lda + c0;
        boff[j] = (size_t)(n0 + r0 + j * 32) * ldb + c0;
    }

    f32x4 acc[4][4];
#pragma unroll
    for (int mi = 0; mi < 4; mi++)
#pragma unroll
        for (int nj = 0; nj < 4; nj++)
#pragma unroll
            for (int r = 0; r < 4; r++) acc[mi][nj][r] = 0.f;

    for (int k0 = 0; k0 < K; k0 += 64) {
#pragma unroll
        for (int j = 0; j < 4; j++) {
            gl16(A + aoff[j] + k0, As + j * 2048 + wav * 512);
            gl16(B + boff[j] + k0, Bs + j * 2048 + wav * 512);
        }
        __syncthreads();

#pragma unroll
        for (int ks = 0; ks < 2; ks++) {
            f16x8 a[4], b[4];
#pragma unroll
            for (int mi = 0; mi < 4; mi++) {
                const int row = bm + (mi << 4) + l15;
                const int off = (row << 6) + ((((ks << 2) + lq) ^ (row & 7)) << 3);
                a[mi] = *(const f16x8*)&As[off];
            }
#pragma unroll
            for (int nj = 0; nj < 4; nj++) {
                const int row = bn + (nj << 4) + l15;
                const int off = (row << 6) + ((((ks << 2) + lq) ^ (row & 7)) << 3);
                b[nj] = *(const f16x8*)&Bs[off];
            }
#pragma unroll
            for (int mi = 0; mi < 4; mi++)
#pragma unroll
                for (int nj = 0; nj < 4; nj++)
                    acc[mi][nj] = mfma16q(a[mi], b[nj], acc[mi][nj]);
        }
        __syncthreads();
    }

    // ---- epilogue: 16x16 C/D layout col=lane&15, row=(lane>>4)*4+reg ----
    const long coff = (long)bz * sC;
#pragma unroll
    for (int mi = 0; mi < 4; mi++)
#pragma unroll
        for (int nj = 0; nj < 4; nj++) {
            const int col = n0 + bn + nj * 16 + l15;
#pragma unroll
            for (int r = 0; r < 4; r++) {
                const int row = m0 + bm + mi * 16 + lq * 4 + r;
                C[(size_t)(coff + (long)row * ldc + col)] = f2h(acc[mi][nj][r]);
            }
        }
}

// ---- PV GEMM, occupancy-tuned: C[M,N] = P[M,K] * vT[N,K]^T ----
__global__ __launch_bounds__(256) void gemm_pv64(
    const u16* __restrict__ A_, const u16* __restrict__ B_,
    void* __restrict__ Cp, const int* __restrict__ flagp,
    int K, int lda, int ldb, int ldc, long sA, long sB, long sC, long cbase)
{
    const int tid = threadIdx.x;
    const int lane = tid & 63;
    const int wid = tid >> 6;            // 0..3
    const int wm = wid & 1;              // M half (32 rows)
    const int wn = wid >> 1;             // N half (64 cols)
    const int l15 = lane & 15, lq = lane >> 4;

    // z-fold chunked XCD swizzle (total = 128c, % 8 == 0)
    const int gx = gridDim.x, gy = gridDim.y;
    const int total = gx * gy * gridDim.z;
    const int chunk = total >> 3;
    int lin = (blockIdx.z * gy + blockIdx.y) * gx + blockIdx.x;
    lin = (lin & 7) * chunk + (lin >> 3);
    const int bx = lin % gx;
    const int by = (lin / gx) % gy;
    const int bz = lin / (gx * gy);

    const int m0 = by * 64, n0 = bx * 128;

    const u16* A = A_ + (size_t)bz * sA;
    const u16* B = B_ + (size_t)bz * sB;

    __shared__ __align__(16) u16 As[64 * 64];    //  8 KiB
    __shared__ __align__(16) u16 Bs[128 * 64];   // 16 KiB

    const int r0 = tid >> 3;
    const int c0 = ((tid & 7) ^ (r0 & 7)) * 8;
    size_t aoff[2], boff[4];
#pragma unroll
    for (int j = 0; j < 2; j++)
        aoff[j] = (size_t)(m0 + j * 32 + r0) * lda + c0;
#pragma unroll
    for (int j = 0; j < 4; j++)
        boff[j] = (size_t)(n0 + j * 32 + r0) * ldb + c0;

    f32x4 acc[2][4];
#pragma unroll
    for (int h = 0; h < 2; h++)
#pragma unroll
        for (int nj = 0; nj < 4; nj++)
#pragma unroll
            for (int r = 0; r < 4; r++) acc[h][nj][r] = 0.f;

    for (int k0 = 0; k0 < K; k0 += 64) {
#pragma unroll
        for (int j = 0; j < 2; j++)
            gl16(A + aoff[j] + k0, As + j * 2048 + (tid & 63) * 8 + (tid >> 6) * 512);
#pragma unroll
        for (int j = 0; j < 4; j++)
            gl16(B + boff[j] + k0, Bs + j * 2048 + (tid & 63) * 8 + (tid >> 6) * 512);
        __syncthreads();

#pragma unroll
        for (int ks = 0; ks < 2; ks++) {
            f16x8 a[2], b[4];
#pragma unroll
            for (int h = 0; h < 2; h++) {
                const int row = wm * 32 + h * 16 + l15;
                const int off = (row << 6) + ((((ks << 2) + lq) ^ (row & 7)) << 3);
                a[h] = *(const f16x8*)&As[off];
            }
#pragma unroll
            for (int nj = 0; nj < 4; nj++) {
                const int row = wn * 64 + nj * 16 + l15;
                const int off = (row << 6) + ((((ks << 2) + lq) ^ (row & 7)) << 3);
                b[nj] = *(const f16x8*)&Bs[off];
            }
#pragma unroll
            for (int h = 0; h < 2; h++)
#pragma unroll
                for (int nj = 0; nj < 4; nj++)
                    acc[h][nj] = mfma16q(a[h], b[nj], acc[h][nj]);
        }
        __syncthreads();
    }

    // ---- epilogue: 16x16 C/D layout col=lane&15, row=(lane>>4)*4+reg ----
    const int isbf = *flagp;
    float* Cf = (float*)Cp;
    u16* Cb = (u16*)Cp;
    const long coff = cbase + (long)bz * sC;
#pragma unroll
    for (int h = 0; h < 2; h++)
#pragma unroll
        for (int nj = 0; nj < 4; nj++) {
            const int col = n0 + wn * 64 + nj * 16 + l15;
#pragma unroll
            for (int r = 0; r < 4; r++) {
                const int row = m0 + wm * 32 + h * 16 + lq * 4 + r;
                const size_t idx = (size_t)(coff + (long)row * ldc + col);
                if (isbf) Cb[idx] = f2bf(acc[h][nj][r]);
                else Cf[idx] = acc[h][nj][r];
            }
        }
}

// ---- softmax: fp16 row -> fp16 P in place (compact u16 arena) ----
__global__ __launch_bounds__(256) void softmax_k(u16* __restrict__ sc)
{
    u16* srow = sc + (size_t)blockIdx.x * S_LEN;
    const int tid = threadIdx.x;

    f16x8 v = ((const f16x8*)srow)[tid];
    float f[8];
#pragma unroll
    for (int j = 0; j < 8; j++) f[j] = (float)v[j];

    float m = f[0];
#pragma unroll
    for (int j = 1; j < 8; j++) m = fmaxf(m, f[j]);
#pragma unroll
    for (int off = 32; off > 0; off >>= 1) m = fmaxf(m, __shfl_down(m, off));

    __shared__ float redm[4], reds[4];
    if ((tid & 63) == 0) redm[tid >> 6] = m;
    __syncthreads();
    m = fmaxf(fmaxf(redm[0], redm[1]), fmaxf(redm[2], redm[3]));

    float s = 0.f;
#pragma unroll
    for (int j = 0; j < 8; j++) { f[j] = __expf(f[j] - m); s += f[j]; }
#pragma unroll
    for (int off = 32; off > 0; off >>= 1) s += __shfl_down(s, off);
    if ((tid & 63) == 0) reds[tid >> 6] = s;
    __syncthreads();
    s = reds[0] + reds[1] + reds[2] + reds[3];

    const float inv = 1.0f / s;
    f16x8 p;
#pragma unroll
    for (int j = 0; j < 8; j++) p[j] = (_Float16)(f[j] * inv);
    ((f16x8*)srow)[tid] = p;
}

extern "C" void kernel_launch(void* const* d_in, const int* in_sizes, int n_in,
                              void* d_out, int out_size, void* d_ws, size_t ws_size,
                              hipStream_t stream)
{
    const void* x  = d_in[0];
    const void* Wq = d_in[1]; const void* bq = d_in[2];
    const void* Wk = d_in[3]; const void* bk = d_in[4];
    const void* Wv = d_in[5]; const void* bv = d_in[6];

    const int S = S_LEN, D = D_DIM;
    const long SD = (long)S * D;                      // 1,048,576

    char* w = (char*)d_ws;
    int*   flag = (int*)w;                            // @0
    u16*   WT   = (u16*)(w + 1024);                   // 1,572,864
    float* bcat = (float*)(w + 1573888);              // 6,144
    u16*   xf   = (u16*)(w + 1580032);                // 16,777,216
    u16*   qf   = (u16*)(w + 18357248);
    u16*   kf   = (u16*)(w + 35134464);
    u16*   vT   = (u16*)(w + 51911680);               // [512][16384]
    u16*   scP  = (u16*)(w + 68688896);               // fp16 scores arena

    const size_t avail = ws_size > 68688896ull ? ws_size - 68688896ull : 0;
    const size_t perb = (size_t)S * S * 2;            // fp16
    const int c = avail >= 8 * perb ? 8 : avail >= 4 * perb ? 4 : avail >= 2 * perb ? 2 : 1;

    dim3 blk(256);

    detect_k<<<1, 64, 0, stream>>>((const u16*)x, flag);
    cvt_x<<<8192, blk, 0, stream>>>(x, xf, flag);
    pack_w<<<dim3(512, 6), blk, 0, stream>>>(Wq, Wk, Wv, WT, flag);
    pack_bias<<<6, blk, 0, stream>>>(bq, bk, bv, bcat, flag);

    // fused q|k|v projection: [16384,512] x [512,1536]^T(packed WT)
    gemm_f16<2><<<dim3(12, 128, 1), blk, 0, stream>>>(
        xf, WT, nullptr, bcat, qf, kf, vT, flag,
        512, 512, 512, 0, 0, 0, 0, 0);

    for (int cb = 0; cb < B_N; cb += c) {
        const size_t off = (size_t)cb * SD;
        // scores = q k^T (fp16 compact, conflict-free 16x16 frags)
        gemm_sc<<<dim3(16, 16, c), blk, 0, stream>>>(
            qf + off, kf + off, scP,
            512, 512, 512, S, SD, SD, (long)S * S);
        softmax_k<<<c * S, blk, 0, stream>>>(scP);
        // out = P @ v via vT rows; P fp16 compact (lda = S); BM=64 tiles
        gemm_pv64<<<dim3(4, 32, c), blk, 0, stream>>>(
            scP, vT + (size_t)cb * S, d_out, flag,
            S, S, B_N * S, D, (long)S * S, S, SD, (long)cb * SD);
    }
}

// Round 16
// 249.000 us; speedup vs baseline: 1.0104x; 1.0104x over previous
//
#include <hip/hip_runtime.h>
#include <hip/hip_fp16.h>

// Self-attention B=8 S=2048 D=512, fp32-vs-bf16 input auto-detect.
// R24 = R23 resubmit (container infra died twice before verification --
// same mode as rounds 2/9, both of which verified clean on resubmit).
// Source re-audited: gemm_pj skeleton byte-identical to verified gemm_sc;
// epilogue maps cover the 128x128 tile exactly once; v-transpose verbatim
// R14/R22; swizzle total 1536 % 8 == 0; uniform control flow.
// R23 = R22 (251.6 us, best counters) + proj ported to the conflict-free
// 16x16x32 fragment structure (gemm_pj = gemm_sc skeleton + EPI2 epilogue).
// R22 verified the lever at dispatch level: scores 57.2->50.2us, bank
// conflicts 4.19M->0, MfmaUtil 23.7->27 (e2e flat -- noise band +-3us).
// Decision rule: per-dispatch gain without e2e gain again => app is
// serialization-bound => revert to best and declare plateau.
// History: R13 xy-swz; R14 v-transpose; R15/R19 z-fold; R20 fp16 scores
// -22us; R21 pv64; R22 16x16 scores; R9/R11/R12/R16/R18 regressed.

typedef unsigned short u16;
typedef unsigned int u32;
typedef __attribute__((ext_vector_type(8))) _Float16 f16x8;
typedef __attribute__((ext_vector_type(4))) float f32x4;

#define S_LEN 2048
#define D_DIM 512
#define B_N 8

__device__ __forceinline__ u16 f2bf(float f) {
    u32 u = __float_as_uint(f);
    u32 r = u + 0x7FFFu + ((u >> 16) & 1u);   // RNE
    return (u16)(r >> 16);
}
__device__ __forceinline__ float bf2f(u16 h) {
    return __uint_as_float((u32)h << 16);
}
__device__ __forceinline__ u16 f2h(float f) {
    _Float16 h = (_Float16)f;                 // RNE
    return *(u16*)&h;
}
__device__ __forceinline__ void gl16(const u16* g, u16* l) {
    __builtin_amdgcn_global_load_lds(
        (const __attribute__((address_space(1))) void*)g,
        (__attribute__((address_space(3))) void*)l, 16, 0, 0);
}
__device__ __forceinline__ f32x4 mfma16q(f16x8 a, f16x8 b, f32x4 c) {
    return __builtin_amdgcn_mfma_f32_16x16x32_f16(a, b, c, 0, 0, 0);
}

// ---- dtype detector ----
__global__ void detect_k(const u16* __restrict__ x, int* __restrict__ flag)
{
    int t = threadIdx.x;
    u16 u = x[2 * t];
    int e = (u >> 7) & 0xFF;
    int sane = (e == 0) || (e >= 110 && e <= 140);
    unsigned long long b = __ballot(sane);
    if (t == 0) *flag = (__popcll(b) >= 32) ? 1 : 0;
}

// ---- convert x to fp16 ----
__global__ __launch_bounds__(256) void cvt_x(
    const void* __restrict__ X, u16* __restrict__ xf,
    const int* __restrict__ flagp)
{
    const size_t i4 = ((size_t)blockIdx.x * 256 + threadIdx.x) * 4;
    float f[4];
    if (*flagp) {
        ushort4 u = *(const ushort4*)((const u16*)X + i4);
        f[0] = bf2f(u.x); f[1] = bf2f(u.y); f[2] = bf2f(u.z); f[3] = bf2f(u.w);
    } else {
        float4 ff = *(const float4*)((const float*)X + i4);
        f[0] = ff.x; f[1] = ff.y; f[2] = ff.z; f[3] = ff.w;
    }
    ushort4 h;
    h.x = f2h(f[0]); h.y = f2h(f[1]); h.z = f2h(f[2]); h.w = f2h(f[3]);
    *(ushort4*)(xf + i4) = h;
}

// ---- pack W^T concat (q|k|v) fp16: WT[n 0..1535][k 0..511] ----
__global__ __launch_bounds__(256) void pack_w(
    const void* __restrict__ Wq, const void* __restrict__ Wk, const void* __restrict__ Wv,
    u16* __restrict__ WT, const int* __restrict__ flagp)
{
    const int k = blockIdx.x;
    const int n = blockIdx.y * 256 + threadIdx.x;
    const void* W = n < 512 ? Wq : n < 1024 ? Wk : Wv;
    const int nc = n & 511;
    float f = *flagp ? bf2f(((const u16*)W)[(size_t)k * 512 + nc])
                     : ((const float*)W)[(size_t)k * 512 + nc];
    WT[(size_t)n * 512 + k] = f2h(f);
}

__global__ void pack_bias(
    const void* __restrict__ bq, const void* __restrict__ bk, const void* __restrict__ bv,
    float* __restrict__ bcat, const int* __restrict__ flagp)
{
    const int t = blockIdx.x * 256 + threadIdx.x;
    const void* b = t < 512 ? bq : t < 1024 ? bk : bv;
    const int i = t & 511;
    bcat[t] = *flagp ? bf2f(((const u16*)b)[i]) : ((const float*)b)[i];
}

// ---- proj GEMM, conflict-free 16x16 frags: q|k|vT +bias ----
// 128x128 tile, 4 waves (wave = 64x64 = 4x4 frags of 16x16x32), BK=64.
// Staging slot s of row r holds global chunk s^(r&7); XOR reads verified
// conflict-free (R11/R18/pv64/gemm_sc). z-fold XCD swizzle (total=1536).
// mode 0/1: q/k direct stores. mode 2: v LDS-transpose -> coalesced vT.
__global__ __launch_bounds__(256) void gemm_pj(
    const u16* __restrict__ A_, const u16* __restrict__ B_,
    const float* __restrict__ biasf,
    u16* __restrict__ Oq, u16* __restrict__ Ok, u16* __restrict__ OvT,
    int K, int lda, int ldb)
{
    const int tid = threadIdx.x;
    const int lane = tid & 63, wav = tid >> 6;
    const int l15 = lane & 15, lq = lane >> 4;
    const int bm = (wav >> 1) * 64, bn = (wav & 1) * 64;

    // z-fold chunked XCD swizzle (total = 1536, % 8 == 0)
    const int gx = gridDim.x, gy = gridDim.y;
    const int total = gx * gy * gridDim.z;
    const int chunk = total >> 3;
    int lin = (blockIdx.z * gy + blockIdx.y) * gx + blockIdx.x;
    lin = (lin & 7) * chunk + (lin >> 3);
    const int bx = lin % gx;
    const int by = (lin / gx) % gy;

    const int m0 = by * 128, n0 = bx * 128;

    // 32 KiB union: K-loop uses As|Bs halves; v-mode reuses all of it
    // as a 128x128 fp16 transpose buffer after the final barrier.
    __shared__ __align__(16) u16 sh[16384];
    u16* As = sh;
    u16* Bs = sh + 8192;

    const int r0 = tid >> 3;
    const int c0 = ((tid & 7) ^ (r0 & 7)) * 8;
    size_t aoff[4], boff[4];
#pragma unroll
    for (int j = 0; j < 4; j++) {
        aoff[j] = (size_t)(m0 + r0 + j * 32) * lda + c0;
        boff[j] = (size_t)(n0 + r0 + j * 32) * ldb + c0;
    }

    f32x4 acc[4][4];
#pragma unroll
    for (int mi = 0; mi < 4; mi++)
#pragma unroll
        for (int nj = 0; nj < 4; nj++)
#pragma unroll
            for (int r = 0; r < 4; r++) acc[mi][nj][r] = 0.f;

    for (int k0 = 0; k0 < K; k0 += 64) {
#pragma unroll
        for (int j = 0; j < 4; j++) {
            gl16(A_ + aoff[j] + k0, As + j * 2048 + wav * 512);
            gl16(B_ + boff[j] + k0, Bs + j * 2048 + wav * 512);
        }
        __syncthreads();

#pragma unroll
        for (int ks = 0; ks < 2; ks++) {
            f16x8 a[4], b[4];
#pragma unroll
            for (int mi = 0; mi < 4; mi++) {
                const int row = bm + (mi << 4) + l15;
                const int off = (row << 6) + ((((ks << 2) + lq) ^ (row & 7)) << 3);
                a[mi] = *(const f16x8*)&As[off];
            }
#pragma unroll
            for (int nj = 0; nj < 4; nj++) {
                const int row = bn + (nj << 4) + l15;
                const int off = (row << 6) + ((((ks << 2) + lq) ^ (row & 7)) << 3);
                b[nj] = *(const f16x8*)&Bs[off];
            }
#pragma unroll
            for (int mi = 0; mi < 4; mi++)
#pragma unroll
                for (int nj = 0; nj < 4; nj++)
                    acc[mi][nj] = mfma16q(a[mi], b[nj], acc[mi][nj]);
        }
        __syncthreads();
    }

    // ---- epilogue: 16x16 C/D layout col=lane&15, row=(lane>>4)*4+reg ----
    const int mode = bx >> 2;   // 0=q 1=k 2=v (logical bx)
    if (mode == 2) {
        // v: transpose 128x128 tile through LDS, coalesced vT stores.
        // T(lc,row) at sh[lc*128 + (row ^ ((lc&15)<<3))] -- elementwise,
        // layout-independent of fragment shape (same map as R14).
#pragma unroll
        for (int mi = 0; mi < 4; mi++)
#pragma unroll
            for (int nj = 0; nj < 4; nj++) {
                const int lc = bn + nj * 16 + l15;              // 0..127
                const float badd = biasf[n0 + lc];
#pragma unroll
                for (int r = 0; r < 4; r++) {
                    const int row = bm + mi * 16 + lq * 4 + r;  // 0..127
                    sh[lc * 128 + (row ^ ((lc & 15) << 3))] =
                        f2h(acc[mi][nj][r] + badd);
                }
            }
        __syncthreads();
        const int vbase = n0 - 1024;                            // v col offset
#pragma unroll
        for (int p = 0; p < 8; p++) {
            const int q = p * 256 + tid;                        // 0..2047
            const int lc = q >> 4, ch = q & 15;
            const int g = ch ^ (lc & 15);
            f16x8 val = *(const f16x8*)&sh[lc * 128 + g * 8];
            *(f16x8*)&OvT[(size_t)(vbase + lc) * 16384 + m0 + ch * 8] = val;
        }
    } else {
#pragma unroll
        for (int mi = 0; mi < 4; mi++)
#pragma unroll
            for (int nj = 0; nj < 4; nj++) {
                const int gcol = n0 + bn + nj * 16 + l15;
                const int lcol = gcol & 511;
                const float badd = biasf[gcol];
#pragma unroll
                for (int r = 0; r < 4; r++) {
                    const int row = m0 + bm + mi * 16 + lq * 4 + r;
                    const float v = acc[mi][nj][r] + badd;
                    if (mode == 0) Oq[(size_t)row * 512 + lcol] = f2h(v);
                    else           Ok[(size_t)row * 512 + lcol] = f2h(v);
                }
            }
    }
}

// ---- scores GEMM, conflict-free 16x16 frags: C[M,N] = q k^T, fp16 out ----
__global__ __launch_bounds__(256) void gemm_sc(
    const u16* __restrict__ A_, const u16* __restrict__ B_,
    u16* __restrict__ C,
    int K, int lda, int ldb, int ldc, long sA, long sB, long sC)
{
    const int tid = threadIdx.x;
    const int lane = tid & 63, wav = tid >> 6;
    const int l15 = lane & 15, lq = lane >> 4;
    const int bm = (wav >> 1) * 64, bn = (wav & 1) * 64;

    // z-fold chunked XCD swizzle (total = 256c, % 8 == 0)
    const int gx = gridDim.x, gy = gridDim.y;
    const int total = gx * gy * gridDim.z;
    const int chunk = total >> 3;
    int lin = (blockIdx.z * gy + blockIdx.y) * gx + blockIdx.x;
    lin = (lin & 7) * chunk + (lin >> 3);
    const int bx = lin % gx;
    const int by = (lin / gx) % gy;
    const int bz = lin / (gx * gy);

    const int m0 = by * 128, n0 = bx * 128;

    const u16* A = A_ + (size_t)bz * sA;
    const u16* B = B_ + (size_t)bz * sB;

    __shared__ __align__(16) u16 As[8192], Bs[8192];   // 128 x 64 fp16 each

    const int r0 = tid >> 3;
    const int c0 = ((tid & 7) ^ (r0 & 7)) * 8;
    size_t aoff[4], boff[4];
#pragma unroll
    for (int j = 0; j < 4; j++) {
        aoff[j] = (size_t)(m0 + r0 + j * 32) * lda + c0;
        boff[j] = (size_t)(n0 + r0 + j * 32) * ldb + c0;
    }

    f32x4 acc[4][4];
#pragma unroll
    for (int mi = 0; mi < 4; mi++)
#pragma unroll
        for (int nj = 0; nj < 4; nj++)
#pragma unroll
            for (int r = 0; r < 4; r++) acc[mi][nj][r] = 0.f;

    for (int k0 = 0; k0 < K; k0 += 64) {
#pragma unroll
        for (int j = 0; j < 4; j++) {
            gl16(A + aoff[j] + k0, As + j * 2048 + wav * 512);
            gl16(B + boff[j] + k0, Bs + j * 2048 + wav * 512);
        }
        __syncthreads();

#pragma unroll
        for (int ks = 0; ks < 2; ks++) {
            f16x8 a[4], b[4];
#pragma unroll
            for (int mi = 0; mi < 4; mi++) {
                const int row = bm + (mi << 4) + l15;
                const int off = (row << 6) + ((((ks << 2) + lq) ^ (row & 7)) << 3);
                a[mi] = *(const f16x8*)&As[off];
            }
#pragma unroll
            for (int nj = 0; nj < 4; nj++) {
                const int row = bn + (nj << 4) + l15;
                const int off = (row << 6) + ((((ks << 2) + lq) ^ (row & 7)) << 3);
                b[nj] = *(const f16x8*)&Bs[off];
            }
#pragma unroll
            for (int mi = 0; mi < 4; mi++)
#pragma unroll
                for (int nj = 0; nj < 4; nj++)
                    acc[mi][nj] = mfma16q(a[mi], b[nj], acc[mi][nj]);
        }
        __syncthreads();
    }

    // ---- epilogue: 16x16 C/D layout col=lane&15, row=(lane>>4)*4+reg ----
    const long coff = (long)bz * sC;
#pragma unroll
    for (int mi = 0; mi < 4; mi++)
#pragma unroll
        for (int nj = 0; nj < 4; nj++) {
            const int col = n0 + bn + nj * 16 + l15;
#pragma unroll
            for (int r = 0; r < 4; r++) {
                const int row = m0 + bm + mi * 16 + lq * 4 + r;
                C[(size_t)(coff + (long)row * ldc + col)] = f2h(acc[mi][nj][r]);
            }
        }
}

// ---- PV GEMM, occupancy-tuned: C[M,N] = P[M,K] * vT[N,K]^T ----
__global__ __launch_bounds__(256) void gemm_pv64(
    const u16* __restrict__ A_, const u16* __restrict__ B_,
    void* __restrict__ Cp, const int* __restrict__ flagp,
    int K, int lda, int ldb, int ldc, long sA, long sB, long sC, long cbase)
{
    const int tid = threadIdx.x;
    const int lane = tid & 63;
    const int wid = tid >> 6;            // 0..3
    const int wm = wid & 1;              // M half (32 rows)
    const int wn = wid >> 1;             // N half (64 cols)
    const int l15 = lane & 15, lq = lane >> 4;

    // z-fold chunked XCD swizzle (total = 128c, % 8 == 0)
    const int gx = gridDim.x, gy = gridDim.y;
    const int total = gx * gy * gridDim.z;
    const int chunk = total >> 3;
    int lin = (blockIdx.z * gy + blockIdx.y) * gx + blockIdx.x;
    lin = (lin & 7) * chunk + (lin >> 3);
    const int bx = lin % gx;
    const int by = (lin / gx) % gy;
    const int bz = lin / (gx * gy);

    const int m0 = by * 64, n0 = bx * 128;

    const u16* A = A_ + (size_t)bz * sA;
    const u16* B = B_ + (size_t)bz * sB;

    __shared__ __align__(16) u16 As[64 * 64];    //  8 KiB
    __shared__ __align__(16) u16 Bs[128 * 64];   // 16 KiB

    const int r0 = tid >> 3;
    const int c0 = ((tid & 7) ^ (r0 & 7)) * 8;
    size_t aoff[2], boff[4];
#pragma unroll
    for (int j = 0; j < 2; j++)
        aoff[j] = (size_t)(m0 + j * 32 + r0) * lda + c0;
#pragma unroll
    for (int j = 0; j < 4; j++)
        boff[j] = (size_t)(n0 + j * 32 + r0) * ldb + c0;

    f32x4 acc[2][4];
#pragma unroll
    for (int h = 0; h < 2; h++)
#pragma unroll
        for (int nj = 0; nj < 4; nj++)
#pragma unroll
            for (int r = 0; r < 4; r++) acc[h][nj][r] = 0.f;

    for (int k0 = 0; k0 < K; k0 += 64) {
#pragma unroll
        for (int j = 0; j < 2; j++)
            gl16(A + aoff[j] + k0, As + j * 2048 + (tid & 63) * 8 + (tid >> 6) * 512);
#pragma unroll
        for (int j = 0; j < 4; j++)
            gl16(B + boff[j] + k0, Bs + j * 2048 + (tid & 63) * 8 + (tid >> 6) * 512);
        __syncthreads();

#pragma unroll
        for (int ks = 0; ks < 2; ks++) {
            f16x8 a[2], b[4];
#pragma unroll
            for (int h = 0; h < 2; h++) {
                const int row = wm * 32 + h * 16 + l15;
                const int off = (row << 6) + ((((ks << 2) + lq) ^ (row & 7)) << 3);
                a[h] = *(const f16x8*)&As[off];
            }
#pragma unroll
            for (int nj = 0; nj < 4; nj++) {
                const int row = wn * 64 + nj * 16 + l15;
                const int off = (row << 6) + ((((ks << 2) + lq) ^ (row & 7)) << 3);
                b[nj] = *(const f16x8*)&Bs[off];
            }
#pragma unroll
            for (int h = 0; h < 2; h++)
#pragma unroll
                for (int nj = 0; nj < 4; nj++)
                    acc[h][nj] = mfma16q(a[h], b[nj], acc[h][nj]);
        }
        __syncthreads();
    }

    // ---- epilogue: 16x16 C/D layout col=lane&15, row=(lane>>4)*4+reg ----
    const int isbf = *flagp;
    float* Cf = (float*)Cp;
    u16* Cb = (u16*)Cp;
    const long coff = cbase + (long)bz * sC;
#pragma unroll
    for (int h = 0; h < 2; h++)
#pragma unroll
        for (int nj = 0; nj < 4; nj++) {
            const int col = n0 + wn * 64 + nj * 16 + l15;
#pragma unroll
            for (int r = 0; r < 4; r++) {
                const int row = m0 + wm * 32 + h * 16 + lq * 4 + r;
                const size_t idx = (size_t)(coff + (long)row * ldc + col);
                if (isbf) Cb[idx] = f2bf(acc[h][nj][r]);
                else Cf[idx] = acc[h][nj][r];
            }
        }
}

// ---- softmax: fp16 row -> fp16 P in place (compact u16 arena) ----
__global__ __launch_bounds__(256) void softmax_k(u16* __restrict__ sc)
{
    u16* srow = sc + (size_t)blockIdx.x * S_LEN;
    const int tid = threadIdx.x;

    f16x8 v = ((const f16x8*)srow)[tid];
    float f[8];
#pragma unroll
    for (int j = 0; j < 8; j++) f[j] = (float)v[j];

    float m = f[0];
#pragma unroll
    for (int j = 1; j < 8; j++) m = fmaxf(m, f[j]);
#pragma unroll
    for (int off = 32; off > 0; off >>= 1) m = fmaxf(m, __shfl_down(m, off));

    __shared__ float redm[4], reds[4];
    if ((tid & 63) == 0) redm[tid >> 6] = m;
    __syncthreads();
    m = fmaxf(fmaxf(redm[0], redm[1]), fmaxf(redm[2], redm[3]));

    float s = 0.f;
#pragma unroll
    for (int j = 0; j < 8; j++) { f[j] = __expf(f[j] - m); s += f[j]; }
#pragma unroll
    for (int off = 32; off > 0; off >>= 1) s += __shfl_down(s, off);
    if ((tid & 63) == 0) reds[tid >> 6] = s;
    __syncthreads();
    s = reds[0] + reds[1] + reds[2] + reds[3];

    const float inv = 1.0f / s;
    f16x8 p;
#pragma unroll
    for (int j = 0; j < 8; j++) p[j] = (_Float16)(f[j] * inv);
    ((f16x8*)srow)[tid] = p;
}

extern "C" void kernel_launch(void* const* d_in, const int* in_sizes, int n_in,
                              void* d_out, int out_size, void* d_ws, size_t ws_size,
                              hipStream_t stream)
{
    const void* x  = d_in[0];
    const void* Wq = d_in[1]; const void* bq = d_in[2];
    const void* Wk = d_in[3]; const void* bk = d_in[4];
    const void* Wv = d_in[5]; const void* bv = d_in[6];

    const int S = S_LEN, D = D_DIM;
    const long SD = (long)S * D;                      // 1,048,576

    char* w = (char*)d_ws;
    int*   flag = (int*)w;                            // @0
    u16*   WT   = (u16*)(w + 1024);                   // 1,572,864
    float* bcat = (float*)(w + 1573888);              // 6,144
    u16*   xf   = (u16*)(w + 1580032);                // 16,777,216
    u16*   qf   = (u16*)(w + 18357248);
    u16*   kf   = (u16*)(w + 35134464);
    u16*   vT   = (u16*)(w + 51911680);               // [512][16384]
    u16*   scP  = (u16*)(w + 68688896);               // fp16 scores arena

    const size_t avail = ws_size > 68688896ull ? ws_size - 68688896ull : 0;
    const size_t perb = (size_t)S * S * 2;            // fp16
    const int c = avail >= 8 * perb ? 8 : avail >= 4 * perb ? 4 : avail >= 2 * perb ? 2 : 1;

    dim3 blk(256);

    detect_k<<<1, 64, 0, stream>>>((const u16*)x, flag);
    cvt_x<<<8192, blk, 0, stream>>>(x, xf, flag);
    pack_w<<<dim3(512, 6), blk, 0, stream>>>(Wq, Wk, Wv, WT, flag);
    pack_bias<<<6, blk, 0, stream>>>(bq, bk, bv, bcat, flag);

    // fused q|k|v projection: [16384,512] x [512,1536]^T(packed WT)
    gemm_pj<<<dim3(12, 128, 1), blk, 0, stream>>>(
        xf, WT, bcat, qf, kf, vT, 512, 512, 512);

    for (int cb = 0; cb < B_N; cb += c) {
        const size_t off = (size_t)cb * SD;
        // scores = q k^T (fp16 compact, conflict-free 16x16 frags)
        gemm_sc<<<dim3(16, 16, c), blk, 0, stream>>>(
            qf + off, kf + off, scP,
            512, 512, 512, S, SD, SD, (long)S * S);
        softmax_k<<<c * S, blk, 0, stream>>>(scP);
        // out = P @ v via vT rows; P fp16 compact (lda = S); BM=64 tiles
        gemm_pv64<<<dim3(4, 32, c), blk, 0, stream>>>(
            scP, vT + (size_t)cb * S, d_out, flag,
            S, S, B_N * S, D, (long)S * S, S, SD, (long)cb * SD);
    }
}

// Round 17
// 246.527 us; speedup vs baseline: 1.0205x; 1.0100x over previous
//
#include <hip/hip_runtime.h>
#include <hip/hip_fp16.h>

// Self-attention B=8 S=2048 D=512, fp32-vs-bf16 input auto-detect.
// R25 = R24 (249.0 us best) + BK=128 for gemm_sc only (parameter, not
// schedule: halves barrier/drain count 16->8 for the top dispatch; K=512
// -> 4 K-iters of 64 MFMA each). Occupancy objection (m132) weak here:
// counter shows ~2 resident blocks/CU already at 32KB, so 64KB (2
// allocatable) shouldn't cut residency. XOR swizzle generalizes: slot
// s in [0,16) holds chunk s^(r&7) (bit3 preserved); read lanes spread 8
// slots x 4 banks = 32 banks, 2-way free. All else byte-identical R24.
// Decision rule: scores >= 50us or e2e >= 249 => lever null => revert to
// R24 as final, declare measured plateau.
// History: R13 xy-swz; R14 v-transpose; R15/R19 z-fold; R20 fp16 scores
// -22us; R21 pv64; R22/R23 16x16 conflict-free (sc 57->50, proj similar);
// R9/R11/R12/R16/R18 schedule rewrites all regressed.

typedef unsigned short u16;
typedef unsigned int u32;
typedef __attribute__((ext_vector_type(8))) _Float16 f16x8;
typedef __attribute__((ext_vector_type(4))) float f32x4;

#define S_LEN 2048
#define D_DIM 512
#define B_N 8

__device__ __forceinline__ u16 f2bf(float f) {
    u32 u = __float_as_uint(f);
    u32 r = u + 0x7FFFu + ((u >> 16) & 1u);   // RNE
    return (u16)(r >> 16);
}
__device__ __forceinline__ float bf2f(u16 h) {
    return __uint_as_float((u32)h << 16);
}
__device__ __forceinline__ u16 f2h(float f) {
    _Float16 h = (_Float16)f;                 // RNE
    return *(u16*)&h;
}
__device__ __forceinline__ void gl16(const u16* g, u16* l) {
    __builtin_amdgcn_global_load_lds(
        (const __attribute__((address_space(1))) void*)g,
        (__attribute__((address_space(3))) void*)l, 16, 0, 0);
}
__device__ __forceinline__ f32x4 mfma16q(f16x8 a, f16x8 b, f32x4 c) {
    return __builtin_amdgcn_mfma_f32_16x16x32_f16(a, b, c, 0, 0, 0);
}

// ---- dtype detector ----
__global__ void detect_k(const u16* __restrict__ x, int* __restrict__ flag)
{
    int t = threadIdx.x;
    u16 u = x[2 * t];
    int e = (u >> 7) & 0xFF;
    int sane = (e == 0) || (e >= 110 && e <= 140);
    unsigned long long b = __ballot(sane);
    if (t == 0) *flag = (__popcll(b) >= 32) ? 1 : 0;
}

// ---- convert x to fp16 ----
__global__ __launch_bounds__(256) void cvt_x(
    const void* __restrict__ X, u16* __restrict__ xf,
    const int* __restrict__ flagp)
{
    const size_t i4 = ((size_t)blockIdx.x * 256 + threadIdx.x) * 4;
    float f[4];
    if (*flagp) {
        ushort4 u = *(const ushort4*)((const u16*)X + i4);
        f[0] = bf2f(u.x); f[1] = bf2f(u.y); f[2] = bf2f(u.z); f[3] = bf2f(u.w);
    } else {
        float4 ff = *(const float4*)((const float*)X + i4);
        f[0] = ff.x; f[1] = ff.y; f[2] = ff.z; f[3] = ff.w;
    }
    ushort4 h;
    h.x = f2h(f[0]); h.y = f2h(f[1]); h.z = f2h(f[2]); h.w = f2h(f[3]);
    *(ushort4*)(xf + i4) = h;
}

// ---- pack W^T concat (q|k|v) fp16: WT[n 0..1535][k 0..511] ----
__global__ __launch_bounds__(256) void pack_w(
    const void* __restrict__ Wq, const void* __restrict__ Wk, const void* __restrict__ Wv,
    u16* __restrict__ WT, const int* __restrict__ flagp)
{
    const int k = blockIdx.x;
    const int n = blockIdx.y * 256 + threadIdx.x;
    const void* W = n < 512 ? Wq : n < 1024 ? Wk : Wv;
    const int nc = n & 511;
    float f = *flagp ? bf2f(((const u16*)W)[(size_t)k * 512 + nc])
                     : ((const float*)W)[(size_t)k * 512 + nc];
    WT[(size_t)n * 512 + k] = f2h(f);
}

__global__ void pack_bias(
    const void* __restrict__ bq, const void* __restrict__ bk, const void* __restrict__ bv,
    float* __restrict__ bcat, const int* __restrict__ flagp)
{
    const int t = blockIdx.x * 256 + threadIdx.x;
    const void* b = t < 512 ? bq : t < 1024 ? bk : bv;
    const int i = t & 511;
    bcat[t] = *flagp ? bf2f(((const u16*)b)[i]) : ((const float*)b)[i];
}

// ---- proj GEMM, conflict-free 16x16 frags: q|k|vT +bias ----
// 128x128 tile, 4 waves (wave = 64x64 = 4x4 frags of 16x16x32), BK=64.
__global__ __launch_bounds__(256) void gemm_pj(
    const u16* __restrict__ A_, const u16* __restrict__ B_,
    const float* __restrict__ biasf,
    u16* __restrict__ Oq, u16* __restrict__ Ok, u16* __restrict__ OvT,
    int K, int lda, int ldb)
{
    const int tid = threadIdx.x;
    const int lane = tid & 63, wav = tid >> 6;
    const int l15 = lane & 15, lq = lane >> 4;
    const int bm = (wav >> 1) * 64, bn = (wav & 1) * 64;

    // z-fold chunked XCD swizzle (total = 1536, % 8 == 0)
    const int gx = gridDim.x, gy = gridDim.y;
    const int total = gx * gy * gridDim.z;
    const int chunk = total >> 3;
    int lin = (blockIdx.z * gy + blockIdx.y) * gx + blockIdx.x;
    lin = (lin & 7) * chunk + (lin >> 3);
    const int bx = lin % gx;
    const int by = (lin / gx) % gy;

    const int m0 = by * 128, n0 = bx * 128;

    __shared__ __align__(16) u16 sh[16384];
    u16* As = sh;
    u16* Bs = sh + 8192;

    const int r0 = tid >> 3;
    const int c0 = ((tid & 7) ^ (r0 & 7)) * 8;
    size_t aoff[4], boff[4];
#pragma unroll
    for (int j = 0; j < 4; j++) {
        aoff[j] = (size_t)(m0 + r0 + j * 32) * lda + c0;
        boff[j] = (size_t)(n0 + r0 + j * 32) * ldb + c0;
    }

    f32x4 acc[4][4];
#pragma unroll
    for (int mi = 0; mi < 4; mi++)
#pragma unroll
        for (int nj = 0; nj < 4; nj++)
#pragma unroll
            for (int r = 0; r < 4; r++) acc[mi][nj][r] = 0.f;

    for (int k0 = 0; k0 < K; k0 += 64) {
#pragma unroll
        for (int j = 0; j < 4; j++) {
            gl16(A_ + aoff[j] + k0, As + j * 2048 + wav * 512);
            gl16(B_ + boff[j] + k0, Bs + j * 2048 + wav * 512);
        }
        __syncthreads();

#pragma unroll
        for (int ks = 0; ks < 2; ks++) {
            f16x8 a[4], b[4];
#pragma unroll
            for (int mi = 0; mi < 4; mi++) {
                const int row = bm + (mi << 4) + l15;
                const int off = (row << 6) + ((((ks << 2) + lq) ^ (row & 7)) << 3);
                a[mi] = *(const f16x8*)&As[off];
            }
#pragma unroll
            for (int nj = 0; nj < 4; nj++) {
                const int row = bn + (nj << 4) + l15;
                const int off = (row << 6) + ((((ks << 2) + lq) ^ (row & 7)) << 3);
                b[nj] = *(const f16x8*)&Bs[off];
            }
#pragma unroll
            for (int mi = 0; mi < 4; mi++)
#pragma unroll
                for (int nj = 0; nj < 4; nj++)
                    acc[mi][nj] = mfma16q(a[mi], b[nj], acc[mi][nj]);
        }
        __syncthreads();
    }

    // ---- epilogue: 16x16 C/D layout col=lane&15, row=(lane>>4)*4+reg ----
    const int mode = bx >> 2;   // 0=q 1=k 2=v (logical bx)
    if (mode == 2) {
#pragma unroll
        for (int mi = 0; mi < 4; mi++)
#pragma unroll
            for (int nj = 0; nj < 4; nj++) {
                const int lc = bn + nj * 16 + l15;              // 0..127
                const float badd = biasf[n0 + lc];
#pragma unroll
                for (int r = 0; r < 4; r++) {
                    const int row = bm + mi * 16 + lq * 4 + r;  // 0..127
                    sh[lc * 128 + (row ^ ((lc & 15) << 3))] =
                        f2h(acc[mi][nj][r] + badd);
                }
            }
        __syncthreads();
        const int vbase = n0 - 1024;                            // v col offset
#pragma unroll
        for (int p = 0; p < 8; p++) {
            const int q = p * 256 + tid;                        // 0..2047
            const int lc = q >> 4, ch = q & 15;
            const int g = ch ^ (lc & 15);
            f16x8 val = *(const f16x8*)&sh[lc * 128 + g * 8];
            *(f16x8*)&OvT[(size_t)(vbase + lc) * 16384 + m0 + ch * 8] = val;
        }
    } else {
#pragma unroll
        for (int mi = 0; mi < 4; mi++)
#pragma unroll
            for (int nj = 0; nj < 4; nj++) {
                const int gcol = n0 + bn + nj * 16 + l15;
                const int lcol = gcol & 511;
                const float badd = biasf[gcol];
#pragma unroll
                for (int r = 0; r < 4; r++) {
                    const int row = m0 + bm + mi * 16 + lq * 4 + r;
                    const float v = acc[mi][nj][r] + badd;
                    if (mode == 0) Oq[(size_t)row * 512 + lcol] = f2h(v);
                    else           Ok[(size_t)row * 512 + lcol] = f2h(v);
                }
            }
    }
}

// ---- scores GEMM, BK=128, conflict-free 16x16 frags: fp16 out ----
// 128x128 tile, 4 waves, BK=128 (K=512 -> 4 iters, 64 MFMA per barrier
// pair). LDS 64KB: As/Bs [128][128] fp16. Staging pass j: rows j*16+t>>4,
// 16 thr/row x 16B; slot t&15 holds chunk (t&15)^(r&7). Read slot
// sl=ks*4+lq in [0,16): addr row*128 + ((sl^(row&7))*8) -- bit3 of sl
// preserved by the 3-bit XOR, 8 distinct slots x 4 banks = 32 banks.
__global__ __launch_bounds__(256) void gemm_sc(
    const u16* __restrict__ A_, const u16* __restrict__ B_,
    u16* __restrict__ C,
    int K, int lda, int ldb, int ldc, long sA, long sB, long sC)
{
    const int tid = threadIdx.x;
    const int lane = tid & 63, wav = tid >> 6;
    const int l15 = lane & 15, lq = lane >> 4;
    const int bm = (wav >> 1) * 64, bn = (wav & 1) * 64;

    // z-fold chunked XCD swizzle (total = 256c, % 8 == 0)
    const int gx = gridDim.x, gy = gridDim.y;
    const int total = gx * gy * gridDim.z;
    const int chunk = total >> 3;
    int lin = (blockIdx.z * gy + blockIdx.y) * gx + blockIdx.x;
    lin = (lin & 7) * chunk + (lin >> 3);
    const int bx = lin % gx;
    const int by = (lin / gx) % gy;
    const int bz = lin / (gx * gy);

    const int m0 = by * 128, n0 = bx * 128;

    const u16* A = A_ + (size_t)bz * sA;
    const u16* B = B_ + (size_t)bz * sB;

    __shared__ __align__(16) u16 As[16384], Bs[16384];   // 128 x 128 fp16

    // staging: thread t covers row r0 = t>>4 (+j*16), 16B at slot t&15;
    // source col chunk pre-swizzled: (t&15)^(r0&7).
    const int r0 = tid >> 4;                       // 0..15
    const int c0 = (((tid & 15) ^ (r0 & 7))) * 8;  // pre-swizzled source col
    size_t aoff[8], boff[8];
#pragma unroll
    for (int j = 0; j < 8; j++) {
        aoff[j] = (size_t)(m0 + j * 16 + r0) * lda + c0;
        boff[j] = (size_t)(n0 + j * 16 + r0) * ldb + c0;
    }

    f32x4 acc[4][4];
#pragma unroll
    for (int mi = 0; mi < 4; mi++)
#pragma unroll
        for (int nj = 0; nj < 4; nj++)
#pragma unroll
            for (int r = 0; r < 4; r++) acc[mi][nj][r] = 0.f;

    for (int k0 = 0; k0 < K; k0 += 128) {
        // pass j writes 2048 elems linearly: dst elem = j*2048 + t*8
        // (= row-major [j*16 + t>>4][(t&15)*8]); wave-uniform base + lane*16B.
#pragma unroll
        for (int j = 0; j < 8; j++)
            gl16(A + aoff[j] + k0, As + j * 2048 + wav * 512);
#pragma unroll
        for (int j = 0; j < 8; j++)
            gl16(B + boff[j] + k0, Bs + j * 2048 + wav * 512);
        __syncthreads();

#pragma unroll
        for (int ks = 0; ks < 4; ks++) {
            const int sl = (ks << 2) + lq;         // 0..15
            f16x8 a[4], b[4];
#pragma unroll
            for (int mi = 0; mi < 4; mi++) {
                const int row = bm + (mi << 4) + l15;
                const int off = (row << 7) + ((sl ^ (row & 7)) << 3);
                a[mi] = *(const f16x8*)&As[off];
            }
#pragma unroll
            for (int nj = 0; nj < 4; nj++) {
                const int row = bn + (nj << 4) + l15;
                const int off = (row << 7) + ((sl ^ (row & 7)) << 3);
                b[nj] = *(const f16x8*)&Bs[off];
            }
#pragma unroll
            for (int mi = 0; mi < 4; mi++)
#pragma unroll
                for (int nj = 0; nj < 4; nj++)
                    acc[mi][nj] = mfma16q(a[mi], b[nj], acc[mi][nj]);
        }
        __syncthreads();
    }

    // ---- epilogue: 16x16 C/D layout col=lane&15, row=(lane>>4)*4+reg ----
    const long coff = (long)bz * sC;
#pragma unroll
    for (int mi = 0; mi < 4; mi++)
#pragma unroll
        for (int nj = 0; nj < 4; nj++) {
            const int col = n0 + bn + nj * 16 + l15;
#pragma unroll
            for (int r = 0; r < 4; r++) {
                const int row = m0 + bm + mi * 16 + lq * 4 + r;
                C[(size_t)(coff + (long)row * ldc + col)] = f2h(acc[mi][nj][r]);
            }
        }
}

// ---- PV GEMM, occupancy-tuned: C[M,N] = P[M,K] * vT[N,K]^T ----
__global__ __launch_bounds__(256) void gemm_pv64(
    const u16* __restrict__ A_, const u16* __restrict__ B_,
    void* __restrict__ Cp, const int* __restrict__ flagp,
    int K, int lda, int ldb, int ldc, long sA, long sB, long sC, long cbase)
{
    const int tid = threadIdx.x;
    const int lane = tid & 63;
    const int wid = tid >> 6;            // 0..3
    const int wm = wid & 1;              // M half (32 rows)
    const int wn = wid >> 1;             // N half (64 cols)
    const int l15 = lane & 15, lq = lane >> 4;

    // z-fold chunked XCD swizzle (total = 128c, % 8 == 0)
    const int gx = gridDim.x, gy = gridDim.y;
    const int total = gx * gy * gridDim.z;
    const int chunk = total >> 3;
    int lin = (blockIdx.z * gy + blockIdx.y) * gx + blockIdx.x;
    lin = (lin & 7) * chunk + (lin >> 3);
    const int bx = lin % gx;
    const int by = (lin / gx) % gy;
    const int bz = lin / (gx * gy);

    const int m0 = by * 64, n0 = bx * 128;

    const u16* A = A_ + (size_t)bz * sA;
    const u16* B = B_ + (size_t)bz * sB;

    __shared__ __align__(16) u16 As[64 * 64];    //  8 KiB
    __shared__ __align__(16) u16 Bs[128 * 64];   // 16 KiB

    const int r0 = tid >> 3;
    const int c0 = ((tid & 7) ^ (r0 & 7)) * 8;
    size_t aoff[2], boff[4];
#pragma unroll
    for (int j = 0; j < 2; j++)
        aoff[j] = (size_t)(m0 + j * 32 + r0) * lda + c0;
#pragma unroll
    for (int j = 0; j < 4; j++)
        boff[j] = (size_t)(n0 + j * 32 + r0) * ldb + c0;

    f32x4 acc[2][4];
#pragma unroll
    for (int h = 0; h < 2; h++)
#pragma unroll
        for (int nj = 0; nj < 4; nj++)
#pragma unroll
            for (int r = 0; r < 4; r++) acc[h][nj][r] = 0.f;

    for (int k0 = 0; k0 < K; k0 += 64) {
#pragma unroll
        for (int j = 0; j < 2; j++)
            gl16(A + aoff[j] + k0, As + j * 2048 + (tid & 63) * 8 + (tid >> 6) * 512);
#pragma unroll
        for (int j = 0; j < 4; j++)
            gl16(B + boff[j] + k0, Bs + j * 2048 + (tid & 63) * 8 + (tid >> 6) * 512);
        __syncthreads();

#pragma unroll
        for (int ks = 0; ks < 2; ks++) {
            f16x8 a[2], b[4];
#pragma unroll
            for (int h = 0; h < 2; h++) {
                const int row = wm * 32 + h * 16 + l15;
                const int off = (row << 6) + ((((ks << 2) + lq) ^ (row & 7)) << 3);
                a[h] = *(const f16x8*)&As[off];
            }
#pragma unroll
            for (int nj = 0; nj < 4; nj++) {
                const int row = wn * 64 + nj * 16 + l15;
                const int off = (row << 6) + ((((ks << 2) + lq) ^ (row & 7)) << 3);
                b[nj] = *(const f16x8*)&Bs[off];
            }
#pragma unroll
            for (int h = 0; h < 2; h++)
#pragma unroll
                for (int nj = 0; nj < 4; nj++)
                    acc[h][nj] = mfma16q(a[h], b[nj], acc[h][nj]);
        }
        __syncthreads();
    }

    // ---- epilogue: 16x16 C/D layout col=lane&15, row=(lane>>4)*4+reg ----
    const int isbf = *flagp;
    float* Cf = (float*)Cp;
    u16* Cb = (u16*)Cp;
    const long coff = cbase + (long)bz * sC;
#pragma unroll
    for (int h = 0; h < 2; h++)
#pragma unroll
        for (int nj = 0; nj < 4; nj++) {
            const int col = n0 + wn * 64 + nj * 16 + l15;
#pragma unroll
            for (int r = 0; r < 4; r++) {
                const int row = m0 + wm * 32 + h * 16 + lq * 4 + r;
                const size_t idx = (size_t)(coff + (long)row * ldc + col);
                if (isbf) Cb[idx] = f2bf(acc[h][nj][r]);
                else Cf[idx] = acc[h][nj][r];
            }
        }
}

// ---- softmax: fp16 row -> fp16 P in place (compact u16 arena) ----
__global__ __launch_bounds__(256) void softmax_k(u16* __restrict__ sc)
{
    u16* srow = sc + (size_t)blockIdx.x * S_LEN;
    const int tid = threadIdx.x;

    f16x8 v = ((const f16x8*)srow)[tid];
    float f[8];
#pragma unroll
    for (int j = 0; j < 8; j++) f[j] = (float)v[j];

    float m = f[0];
#pragma unroll
    for (int j = 1; j < 8; j++) m = fmaxf(m, f[j]);
#pragma unroll
    for (int off = 32; off > 0; off >>= 1) m = fmaxf(m, __shfl_down(m, off));

    __shared__ float redm[4], reds[4];
    if ((tid & 63) == 0) redm[tid >> 6] = m;
    __syncthreads();
    m = fmaxf(fmaxf(redm[0], redm[1]), fmaxf(redm[2], redm[3]));

    float s = 0.f;
#pragma unroll
    for (int j = 0; j < 8; j++) { f[j] = __expf(f[j] - m); s += f[j]; }
#pragma unroll
    for (int off = 32; off > 0; off >>= 1) s += __shfl_down(s, off);
    if ((tid & 63) == 0) reds[tid >> 6] = s;
    __syncthreads();
    s = reds[0] + reds[1] + reds[2] + reds[3];

    const float inv = 1.0f / s;
    f16x8 p;
#pragma unroll
    for (int j = 0; j < 8; j++) p[j] = (_Float16)(f[j] * inv);
    ((f16x8*)srow)[tid] = p;
}

extern "C" void kernel_launch(void* const* d_in, const int* in_sizes, int n_in,
                              void* d_out, int out_size, void* d_ws, size_t ws_size,
                              hipStream_t stream)
{
    const void* x  = d_in[0];
    const void* Wq = d_in[1]; const void* bq = d_in[2];
    const void* Wk = d_in[3]; const void* bk = d_in[4];
    const void* Wv = d_in[5]; const void* bv = d_in[6];

    const int S = S_LEN, D = D_DIM;
    const long SD = (long)S * D;                      // 1,048,576

    char* w = (char*)d_ws;
    int*   flag = (int*)w;                            // @0
    u16*   WT   = (u16*)(w + 1024);                   // 1,572,864
    float* bcat = (float*)(w + 1573888);              // 6,144
    u16*   xf   = (u16*)(w + 1580032);                // 16,777,216
    u16*   qf   = (u16*)(w + 18357248);
    u16*   kf   = (u16*)(w + 35134464);
    u16*   vT   = (u16*)(w + 51911680);               // [512][16384]
    u16*   scP  = (u16*)(w + 68688896);               // fp16 scores arena

    const size_t avail = ws_size > 68688896ull ? ws_size - 68688896ull : 0;
    const size_t perb = (size_t)S * S * 2;            // fp16
    const int c = avail >= 8 * perb ? 8 : avail >= 4 * perb ? 4 : avail >= 2 * perb ? 2 : 1;

    dim3 blk(256);

    detect_k<<<1, 64, 0, stream>>>((const u16*)x, flag);
    cvt_x<<<8192, blk, 0, stream>>>(x, xf, flag);
    pack_w<<<dim3(512, 6), blk, 0, stream>>>(Wq, Wk, Wv, WT, flag);
    pack_bias<<<6, blk, 0, stream>>>(bq, bk, bv, bcat, flag);

    // fused q|k|v projection: [16384,512] x [512,1536]^T(packed WT)
    gemm_pj<<<dim3(12, 128, 1), blk, 0, stream>>>(
        xf, WT, bcat, qf, kf, vT, 512, 512, 512);

    for (int cb = 0; cb < B_N; cb += c) {
        const size_t off = (size_t)cb * SD;
        // scores = q k^T (fp16 compact, BK=128 conflict-free 16x16 frags)
        gemm_sc<<<dim3(16, 16, c), blk, 0, stream>>>(
            qf + off, kf + off, scP,
            512, 512, 512, S, SD, SD, (long)S * S);
        softmax_k<<<c * S, blk, 0, stream>>>(scP);
        // out = P @ v via vT rows; P fp16 compact (lda = S); BM=64 tiles
        gemm_pv64<<<dim3(4, 32, c), blk, 0, stream>>>(
            scP, vT + (size_t)cb * S, d_out, flag,
            S, S, B_N * S, D, (long)S * S, S, SD, (long)cb * SD);
    }
}